// Round 16
// baseline (47.411 us; speedup 1.0000x reference)
//
#include <hip/hip_runtime.h>

// DifferentiableCIndexLoss:
//   mask[i,j] = (t[i] < t[j]) && (e[i]==1)
//   loss = sum sigmoid((r[j]-r[i])/SIGMA) * mask ;  count = sum mask
//   out  = loss / (count + 1e-6)
//
// R16: bucket-sorted classification REBUILT on the measured R14 skeleton.
// R15 probe: skeleton = 3.9us, math = ~23us of k_main's 27us -> only lever
// >=2x is eliminating dead pairs + mask/count ops on provably-true pairs.
// R15 also showed extra graph nodes cost only their own work (+3.9us for a
// 4us kernel), so multi-node prep is fine (revises R5/R6 conclusion).
//   prep: memset(8KB hist) -> k_pre (64blk, global-atomic 1024-bucket hist)
//         -> k_scan (1blk x1024: dual scan, cursors, chunk/page bounds)
//         -> k_scatter (64blk: E=2^s / F=2^-s transform + bucket sort;
//            within-bucket order arbitrary = still exact, mixed tiles cmp)
//   main: EXACT R14 geometry (1024 blk, RPT=8, chunk=2048, JTILE=64,
//         grid-stride, block-uniform branches). Per tile:
//           jh < rl  -> skip (all-false / empty chunk; before staging)
//           jl > rh  -> ALL-TRUE: fma,fma,mul,rcp,add,fma per 2 pairs
//                       (no cmp/cndmask/count); count analytic nv*64;
//                       pads E=0 contribute exactly 1/col -> subtracted
//           else     -> mixed (~26%): R14 loop verbatim (pads masked)
// Exactness: bucket(t) monotone => strict bucket inequality proves the
// compare incl. boundary values; equal/overlap buckets -> exact cmp.
//   s = r*log2e/sigma clamped +-60; sigmoid = 1/(1+E_i*F_j).
//   1/u+1/v = (u+v)*rcp(u*v); overflow -> rp=0, true contrib ~2^-big: ok.

#define NB 1024
#define BLOCK 256
#define RPT 8
#define CHUNK (BLOCK * RPT)        // 2048
#define MAXRC 8
#define JTILE 64
#define NPG 256                    // 16384/64
#define GRID_MAIN 1024

__device__ __forceinline__ float fast_exp2(float x) { return __builtin_amdgcn_exp2f(x); }
__device__ __forceinline__ float fast_rcp(float x)  { return __builtin_amdgcn_rcpf(x); }
__device__ __forceinline__ float clamp60(float x)   { return fminf(fmaxf(x, -60.0f), 60.0f); }
__device__ __forceinline__ int bucket_of(float tv) {
    int b = (int)(tv * (float)NB);
    return min(max(b, 0), NB - 1);
}

// ---- 1) histogram (global scattered atomics: 1024 addrs, ~16 adds each) -----
__global__ __launch_bounds__(BLOCK) void k_pre(
    const float* __restrict__ t, const int* __restrict__ ev, int B,
    int* __restrict__ histI, int* __restrict__ histJ) {
    int g = blockIdx.x * BLOCK + threadIdx.x;
    if (g >= B) return;
    int b = bucket_of(t[g]);
    atomicAdd(&histJ[b], 1);
    if (ev[g] == 1) atomicAdd(&histI[b], 1);
}

// ---- 2) dual scan + cursors + chunk/page bucket bounds (1 blk x 1024) -------
__global__ __launch_bounds__(1024) void k_scan(
    const int* __restrict__ histI, const int* __restrict__ histJ,
    int* __restrict__ curI, int* __restrict__ curJ,
    int* __restrict__ rcLo, int* __restrict__ rcHi,
    int* __restrict__ jpLo, int* __restrict__ jpHi,
    int* __restrict__ nactive_g) {

    const int tid = threadIdx.x;
    __shared__ int sA[NB], sB[NB];
    __shared__ int rcLo_s[MAXRC], rcHi_s[MAXRC];
    __shared__ int jpLo_s[NPG], jpHi_s[NPG];

    int cI = histI[tid], cJ = histJ[tid];
    sA[tid] = cI; sB[tid] = cJ;
    if (tid < MAXRC) { rcLo_s[tid] = 0x7fffffff; rcHi_s[tid] = -1; }
    if (tid < NPG)   { jpLo_s[tid] = 0x7fffffff; jpHi_s[tid] = -1; }
    __syncthreads();
    for (int off = 1; off < NB; off <<= 1) {      // dual Hillis-Steele
        int a = (tid >= off) ? sA[tid - off] : 0;
        int b = (tid >= off) ? sB[tid - off] : 0;
        __syncthreads();
        sA[tid] += a; sB[tid] += b;
        __syncthreads();
    }
    int exI = sA[tid] - cI, exJ = sB[tid] - cJ;
    curI[tid] = exI; curJ[tid] = exJ;
    if (tid == NB - 1) *nactive_g = sA[NB - 1];
    if (cI > 0) {
        int c0 = exI >> 11, c1 = (exI + cI - 1) >> 11;     // /2048
        for (int c = c0; c <= c1; ++c) { atomicMin(&rcLo_s[c], tid); atomicMax(&rcHi_s[c], tid); }
    }
    if (cJ > 0) {
        int p0 = exJ >> 6, p1 = (exJ + cJ - 1) >> 6;       // /64
        for (int p = p0; p <= p1; ++p) { atomicMin(&jpLo_s[p], tid); atomicMax(&jpHi_s[p], tid); }
    }
    __syncthreads();
    if (tid < MAXRC) { rcLo[tid] = rcLo_s[tid]; rcHi[tid] = rcHi_s[tid]; }
    if (tid < NPG)   { jpLo[tid] = jpLo_s[tid]; jpHi[tid] = jpHi_s[tid]; }
}

// ---- 3) transform + bucket-sort scatter (scattered atomics) -----------------
__global__ __launch_bounds__(BLOCK) void k_scatter(
    const float* __restrict__ r, const float* __restrict__ t,
    const int* __restrict__ ev, int B, float kscale,
    int* __restrict__ curI, int* __restrict__ curJ,
    float2* __restrict__ sI, float2* __restrict__ sJ) {
    int g = blockIdx.x * BLOCK + threadIdx.x;
    if (g >= B) return;
    float tv = t[g];
    float s  = clamp60(r[g] * kscale);
    int b = bucket_of(tv);
    int pj = atomicAdd(&curJ[b], 1);
    sJ[pj] = make_float2(fast_exp2(-s), tv);       // F_j = 2^{-s_j}
    if (ev[g] == 1) {
        int pi = atomicAdd(&curI[b], 1);
        sI[pi] = make_float2(fast_exp2(s), tv);    // E_i = 2^{s_i}
    }
}

// ---- 4) main: R14 skeleton + 3-way classified tiles -------------------------
__global__ __launch_bounds__(BLOCK) void k_main(
    const float2* __restrict__ sI, const float2* __restrict__ sJ,
    const int* __restrict__ rcLo, const int* __restrict__ rcHi,
    const int* __restrict__ jpLo, const int* __restrict__ jpHi,
    const int* __restrict__ nactive_g,
    float* __restrict__ pL, unsigned int* __restrict__ pC) {

    const int tid = threadIdx.x;
    const int nactive = *nactive_g;
    const int nrc = (nactive + CHUNK - 1) / CHUNK;   // ~4
    const int ntiles = nrc * NPG;                     // ~1024

    __shared__ float2 tile[JTILE];

    float lsum = 0.0f;
    int   csum = 0;

    for (int tix = blockIdx.x; tix < ntiles; tix += gridDim.x) {
        int rc = tix >> 8;            // ntiles = nrc*256
        int cg = tix & (NPG - 1);
        int rl = rcLo[rc], rh = rcHi[rc];
        int jh = jpHi[cg];
        if (jh < rl) continue;        // all-false or empty chunk (uniform)
        int jl = jpLo[cg];

        // 8 rows/thread, coalesced; pads: E=0 (u=1 exactly), T=3 (mask off)
        float E[RPT], T[RPT];
        int nv = 0;
        int rbase = rc * CHUNK;
#pragma unroll
        for (int k = 0; k < RPT; ++k) {
            int rr = rbase + tid + (k << 8);
            if (rr < nactive) { float2 f = sI[rr]; E[k] = f.x; T[k] = f.y; ++nv; }
            else              { E[k] = 0.0f; T[k] = 3.0f; }
        }

        __syncthreads();
        if (tid < JTILE) tile[tid] = sJ[(cg << 6) + tid];
        __syncthreads();

        if (jl > rh) {
            // ALL-TRUE: no cmp/cndmask/count; pads contribute exactly 1/col
            float l[4] = {0.f, 0.f, 0.f, 0.f};
#pragma unroll 4
            for (int jj = 0; jj < JTILE; ++jj) {
                float F = tile[jj].x;
#pragma unroll
                for (int g2 = 0; g2 < 4; ++g2) {
                    float u = __builtin_fmaf(E[2*g2],   F, 1.0f);
                    float v = __builtin_fmaf(E[2*g2+1], F, 1.0f);
                    float rp = fast_rcp(u * v);
                    l[g2] = __builtin_fmaf(u + v, rp, l[g2]);
                }
            }
            lsum += ((l[0] + l[1]) + (l[2] + l[3]))
                  - (float)((RPT - nv) << 6);       // remove pad contribution
            csum += nv << 6;                         // analytic count
        } else {
            // MIXED (~26% of tiles): R14 loop verbatim
            float l[4] = {0.f, 0.f, 0.f, 0.f};
            int   c[4] = {0, 0, 0, 0};
#pragma unroll 4
            for (int jj = 0; jj < JTILE; ++jj) {
                float2 q = tile[jj];
                float F = q.x, tj = q.y;
#pragma unroll
                for (int g2 = 0; g2 < 4; ++g2) {
                    float u = __builtin_fmaf(E[2*g2],   F, 1.0f);
                    float v = __builtin_fmaf(E[2*g2+1], F, 1.0f);
                    float rp = fast_rcp(u * v);
                    bool m0 = T[2*g2]   < tj;
                    bool m1 = T[2*g2+1] < tj;
                    float num = (m0 ? v : 0.0f) + (m1 ? u : 0.0f);
                    l[g2] = __builtin_fmaf(num, rp, l[g2]);
                    c[g2] += m0 + m1;
                }
            }
            lsum += (l[0] + l[1]) + (l[2] + l[3]);
            csum += (c[0] + c[1]) + (c[2] + c[3]);
        }
    }

    // block reduce + plain partial stores
#pragma unroll
    for (int off = 32; off > 0; off >>= 1) {
        lsum += __shfl_down(lsum, off);
        csum += __shfl_down(csum, off);
    }
    __shared__ float lw[BLOCK / 64];
    __shared__ int   cw[BLOCK / 64];
    int wid = tid >> 6;
    if ((tid & 63) == 0) { lw[wid] = lsum; cw[wid] = csum; }
    __syncthreads();
    if (tid == 0) {
        pL[blockIdx.x] = (lw[0] + lw[1]) + (lw[2] + lw[3]);
        pC[blockIdx.x] = (unsigned)((cw[0] + cw[1]) + (cw[2] + cw[3]));
    }
}

// ---- 5) finalize -------------------------------------------------------------
__global__ __launch_bounds__(BLOCK) void k_finalize(
    const float* __restrict__ pL, const unsigned int* __restrict__ pC,
    int n, float* __restrict__ out) {
    double l = 0.0, c = 0.0;
    for (int i = threadIdx.x; i < n; i += BLOCK) {
        l += (double)pL[i];
        c += (double)pC[i];
    }
#pragma unroll
    for (int off = 32; off > 0; off >>= 1) {
        l += __shfl_down(l, off);
        c += __shfl_down(c, off);
    }
    __shared__ double lw[BLOCK / 64], cw[BLOCK / 64];
    int wid = threadIdx.x >> 6;
    if ((threadIdx.x & 63) == 0) { lw[wid] = l; cw[wid] = c; }
    __syncthreads();
    if (threadIdx.x == 0) {
        double L = (lw[0] + lw[1]) + (lw[2] + lw[3]);
        double C = (cw[0] + cw[1]) + (cw[2] + cw[3]);
        out[0] = (float)(L / (C + 1e-6));
    }
}

extern "C" void kernel_launch(void* const* d_in, const int* in_sizes, int n_in,
                              void* d_out, int out_size, void* d_ws, size_t ws_size,
                              hipStream_t stream) {
    const float* r  = (const float*)d_in[0];
    const float* t  = (const float*)d_in[1];
    const int*   ev = (const int*)d_in[2];
    float* out = (float*)d_out;
    const int B = in_sizes[0];   // 16384

    const float SIGMA = 0.1f;
    const float LOG2E = 1.4426950408889634f;
    const float kscale = LOG2E / SIGMA;

    char* ws = (char*)d_ws;
    int* histI = (int*)(ws + 0);            // 4 KB (memset)
    int* histJ = (int*)(ws + 4096);         // 4 KB (memset)
    int* curI  = (int*)(ws + 8192);
    int* curJ  = (int*)(ws + 12288);
    int* rcLo  = (int*)(ws + 16384);
    int* rcHi  = (int*)(ws + 16448);
    int* jpLo  = (int*)(ws + 16512);        // 1 KB
    int* jpHi  = (int*)(ws + 17536);        // 1 KB
    int* nactive_g = (int*)(ws + 18560);
    float2* sI = (float2*)(ws + 20480);     // 128 KB
    float2* sJ = (float2*)(ws + 20480 + 131072);
    float*  pL = (float*)(ws + 20480 + 262144);
    unsigned int* pC = (unsigned int*)((char*)pL + GRID_MAIN * 4);

    const int nblk = (B + BLOCK - 1) / BLOCK;   // 64

    hipMemsetAsync(ws, 0, 8192, stream);        // zero both histograms
    k_pre<<<nblk, BLOCK, 0, stream>>>(t, ev, B, histI, histJ);
    k_scan<<<1, 1024, 0, stream>>>(histI, histJ, curI, curJ,
                                   rcLo, rcHi, jpLo, jpHi, nactive_g);
    k_scatter<<<nblk, BLOCK, 0, stream>>>(r, t, ev, B, kscale, curI, curJ, sI, sJ);
    k_main<<<GRID_MAIN, BLOCK, 0, stream>>>(sI, sJ, rcLo, rcHi, jpLo, jpHi,
                                            nactive_g, pL, pC);
    k_finalize<<<1, BLOCK, 0, stream>>>(pL, pC, GRID_MAIN, out);
}